// Round 3
// baseline (83.691 us; speedup 1.0000x reference)
//
#include <hip/hip_runtime.h>
#include <math.h>

#define EPS 1e-9f

// Unified packed partner record:
//   circle j < Nc : (x, y, radius, unused)
//   box    j >= Nc: (x, y, half.x, half.y)
// Built fresh every call (d_ws is re-poisoned by the harness).
__global__ void prep(const float2* __restrict__ cpos,
                     const float*  __restrict__ crad,
                     const float2* __restrict__ apos,
                     const float2* __restrict__ ahalf,
                     float4* __restrict__ P,
                     float2* __restrict__ out,
                     int Nc, int Ntot) {
    int i = blockIdx.x * blockDim.x + threadIdx.x;
    if (i >= Ntot) return;
    if (i < Nc) {
        const float2 p = cpos[i];
        P[i]   = make_float4(p.x, p.y, crad[i], 0.0f);
        out[i] = p;
    } else {
        const float2 a = apos[i - Nc];
        const float2 h = ahalf[i - Nc];
        P[i]   = make_float4(a.x, a.y, h.x, h.y);
        out[i] = a;
    }
}

// Lane-per-body. blockIdx.x = body group (64 bodies), blockIdx.y*4 + wave = j-chunk.
// Each wave handles S=64 partners (uniform j -> scalar dwordx4 loads).
// 4 waves of a block LDS-reduce, then one atomic pair per body per block.
__global__ __launch_bounds__(256)
void collide(const float4* __restrict__ P,
             float* __restrict__ out,
             int Nc, int Ntot, int S) {
    const int lane = threadIdx.x & 63;
    const int w    = threadIdx.x >> 6;
    const int i    = (blockIdx.x << 6) + lane;

    const int chunk = blockIdx.y * 4 + w;
    const int j0 = chunk * S;
    const int j1 = j0 + S;

    float ax = 0.0f, ay = 0.0f;

    const float4 me = P[i];            // per-lane, coalesced

    if (i < Nc) {                      // circle bodies (wave-uniform: Nc % 64 == 0)
        const float px = me.x, py = me.y, ri = me.z;

        // circle partners
        const int e = min(j1, Nc);
        #pragma unroll 4
        for (int j = j0; j < e; ++j) {
            const float4 q = P[j];
            const float dx = px - q.x, dy = py - q.y;
            const float d2 = fmaf(dx, dx, dy * dy);
            const float r  = __builtin_amdgcn_rsqf(d2);
            const float pen = ri + q.z - d2 * r;
            const bool ok = (j != i) && (d2 > EPS) && (pen > 0.0f);
            const float s = ok ? 0.5f * pen * r : 0.0f;
            ax = fmaf(s, dx, ax);
            ay = fmaf(s, dy, ay);
        }
        // box partners (push on circle)
        const int b0 = max(j0, Nc);
        #pragma unroll 4
        for (int j = b0; j < j1; ++j) {
            const float4 q = P[j];
            const float rx = px - q.x, ry = py - q.y;
            const float cx = fminf(fmaxf(rx, -q.z), q.z);
            const float cy = fminf(fmaxf(ry, -q.w), q.w);
            const float dx = rx - cx, dy = ry - cy;
            const float d2 = fmaf(dx, dx, dy * dy);
            const float r  = __builtin_amdgcn_rsqf(d2);
            const float pen = ri - d2 * r;
            const bool ok = (d2 > EPS) && (pen > 0.0f);
            const float s = ok ? 0.5f * pen * r : 0.0f;
            ax = fmaf(s, dx, ax);
            ay = fmaf(s, dy, ay);
        }
    } else {                           // box bodies
        const float bx = me.x, by = me.y, hx = me.z, hy = me.w;

        // circle partners (equal-and-opposite on the box)
        const int e = min(j1, Nc);
        #pragma unroll 4
        for (int j = j0; j < e; ++j) {
            const float4 q = P[j];
            const float rx = q.x - bx, ry = q.y - by;
            const float cx = fminf(fmaxf(rx, -hx), hx);
            const float cy = fminf(fmaxf(ry, -hy), hy);
            const float dx = rx - cx, dy = ry - cy;
            const float d2 = fmaf(dx, dx, dy * dy);
            const float r  = __builtin_amdgcn_rsqf(d2);
            const float pen = q.z - d2 * r;
            const bool ok = (d2 > EPS) && (pen > 0.0f);
            const float s = ok ? -0.5f * pen * r : 0.0f;
            ax = fmaf(s, dx, ax);
            ay = fmaf(s, dy, ay);
        }
        // box partners (minimum-overlap axis)
        const int b0 = max(j0, Nc);
        #pragma unroll 4
        for (int j = b0; j < j1; ++j) {
            const float4 q = P[j];
            const float dax = bx - q.x, day = by - q.y;
            const float ovx = hx + q.z - fabsf(dax);
            const float ovy = hy + q.w - fabsf(day);
            const bool hit = (j != i) && (ovx > 0.0f) && (ovy > 0.0f);
            const bool ux  = ovx <= ovy;
            ax += (hit && ux)  ? 0.5f * ovx * (dax >= 0.0f ? 1.0f : -1.0f) : 0.0f;
            ay += (hit && !ux) ? 0.5f * ovy * (day >= 0.0f ? 1.0f : -1.0f) : 0.0f;
        }
    }

    // block-level reduction: 4 waves -> 1 partial per body
    __shared__ float sax[4][64];
    __shared__ float say[4][64];
    sax[w][lane] = ax;
    say[w][lane] = ay;
    __syncthreads();
    if (w == 0) {
        const float tx = sax[0][lane] + sax[1][lane] + sax[2][lane] + sax[3][lane];
        const float ty = say[0][lane] + say[1][lane] + say[2][lane] + say[3][lane];
        atomicAdd(&out[2 * i],     tx);
        atomicAdd(&out[2 * i + 1], ty);
    }
}

extern "C" void kernel_launch(void* const* d_in, const int* in_sizes, int n_in,
                              void* d_out, int out_size, void* d_ws, size_t ws_size,
                              hipStream_t stream) {
    (void)n_in; (void)out_size; (void)ws_size;

    const float2* cpos  = (const float2*)d_in[0];
    const float*  crad  = (const float*) d_in[1];
    const float2* apos  = (const float2*)d_in[2];
    const float2* ahalf = (const float2*)d_in[3];

    const int Nc   = in_sizes[1];       // 4096
    const int Na   = in_sizes[2] / 2;   // 2048
    const int Ntot = Nc + Na;           // 6144

    float4* P = (float4*)d_ws;

    prep<<<(Ntot + 255) / 256, 256, 0, stream>>>(cpos, crad, apos, ahalf,
                                                 P, (float2*)d_out, Nc, Ntot);

    // 96 body-groups x 24 chunk-blocks x 4 waves -> 96 chunks of S=64 partners
    const int groups = (Ntot + 63) / 64;          // 96
    const int S      = 64;
    const int chunks = (Ntot + S - 1) / S;        // 96
    const int gy     = (chunks + 3) / 4;          // 24
    dim3 grid(groups, gy, 1);
    collide<<<grid, 256, 0, stream>>>(P, (float*)d_out, Nc, Ntot, S);
}

// Round 4
// 78.437 us; speedup vs baseline: 1.0670x; 1.0670x over previous
//
#include <hip/hip_runtime.h>
#include <math.h>

#define EPS 1e-9f

// One block = 64 bodies (lane-per-body, same bodies for all 4 waves) x 256 partners.
//   blockIdx.x : body group (64 bodies)
//   blockIdx.y : partner super-chunk (256 partners, staged in LDS by all 256 threads)
//   wave w     : handles partners [blockIdx.y*256 + w*64, +64)
// Inner loop reads LDS with all lanes of a wave at the same address -> broadcast.
// 4 waves LDS-reduce, then 2 atomics per body per block. out must be zeroed first;
// blockIdx.y==0 blocks add the body's base position so out = pos + sum(corrections).
__global__ __launch_bounds__(256)
void collide(const float2* __restrict__ cpos,
             const float*  __restrict__ crad,
             const float2* __restrict__ apos,
             const float2* __restrict__ ahalf,
             float* __restrict__ out,
             int Nc, int Na) {
    const int Ntot = Nc + Na;
    const int lane = threadIdx.x & 63;
    const int w    = threadIdx.x >> 6;
    const int i    = (blockIdx.x << 6) + lane;          // my body

    // ---- cooperative stage: 256 partners -> LDS ----
    __shared__ float4 PQ[256];
    {
        const int t = threadIdx.x;
        const int p = blockIdx.y * 256 + t;
        float4 v = make_float4(0.f, 0.f, 0.f, 0.f);
        if (p < Nc) {
            const float2 c = cpos[p];
            v = make_float4(c.x, c.y, crad[p], 0.0f);
        } else if (p < Ntot) {
            const float2 a = apos[p - Nc];
            const float2 h = ahalf[p - Nc];
            v = make_float4(a.x, a.y, h.x, h.y);
        }
        PQ[t] = v;
    }
    __syncthreads();

    const int jbase = blockIdx.y * 256 + (w << 6);      // wave's 64-partner chunk
    const bool partners_are_circles = (jbase < Nc);     // chunks are 64-aligned; Nc%64==0
    const int kmax = min(64, Ntot - jbase);             // tail guard (full here)

    float ax = 0.0f, ay = 0.0f;
    float mx = 0.0f, my = 0.0f;                          // my body's fields

    if (i < Nc) {                                        // ---- circle body ----
        const float2 p  = cpos[i];
        const float  ri = crad[i];
        mx = p.x; my = p.y;
        if (partners_are_circles) {
            #pragma unroll 8
            for (int k = 0; k < kmax; ++k) {
                const float4 q = PQ[(w << 6) + k];
                const int j = jbase + k;
                const float dx = p.x - q.x, dy = p.y - q.y;
                const float d2 = fmaf(dx, dx, dy * dy);
                const float r  = __builtin_amdgcn_rsqf(d2);
                const float pen = ri + q.z - d2 * r;
                const bool ok = (j != i) && (d2 > EPS) && (pen > 0.0f);
                const float s = ok ? 0.5f * pen * r : 0.0f;
                ax = fmaf(s, dx, ax);
                ay = fmaf(s, dy, ay);
            }
        } else {
            #pragma unroll 8
            for (int k = 0; k < kmax; ++k) {
                const float4 q = PQ[(w << 6) + k];
                const float rx = p.x - q.x, ry = p.y - q.y;
                const float cx = fminf(fmaxf(rx, -q.z), q.z);
                const float cy = fminf(fmaxf(ry, -q.w), q.w);
                const float dx = rx - cx, dy = ry - cy;
                const float d2 = fmaf(dx, dx, dy * dy);
                const float r  = __builtin_amdgcn_rsqf(d2);
                const float pen = ri - d2 * r;
                const bool ok = (d2 > EPS) && (pen > 0.0f);
                const float s = ok ? 0.5f * pen * r : 0.0f;
                ax = fmaf(s, dx, ax);
                ay = fmaf(s, dy, ay);
            }
        }
    } else if (i < Ntot) {                               // ---- box body ----
        const int ib = i - Nc;
        const float2 a = apos[ib];
        const float2 h = ahalf[ib];
        mx = a.x; my = a.y;
        if (partners_are_circles) {                      // equal-and-opposite on box
            #pragma unroll 8
            for (int k = 0; k < kmax; ++k) {
                const float4 q = PQ[(w << 6) + k];
                const float rx = q.x - a.x, ry = q.y - a.y;
                const float cx = fminf(fmaxf(rx, -h.x), h.x);
                const float cy = fminf(fmaxf(ry, -h.y), h.y);
                const float dx = rx - cx, dy = ry - cy;
                const float d2 = fmaf(dx, dx, dy * dy);
                const float r  = __builtin_amdgcn_rsqf(d2);
                const float pen = q.z - d2 * r;
                const bool ok = (d2 > EPS) && (pen > 0.0f);
                const float s = ok ? -0.5f * pen * r : 0.0f;
                ax = fmaf(s, dx, ax);
                ay = fmaf(s, dy, ay);
            }
        } else {                                         // box-box minimum-overlap axis
            #pragma unroll 8
            for (int k = 0; k < kmax; ++k) {
                const float4 q = PQ[(w << 6) + k];
                const int jb = jbase + k - Nc;
                const float dax = a.x - q.x, day = a.y - q.y;
                const float ovx = h.x + q.z - fabsf(dax);
                const float ovy = h.y + q.w - fabsf(day);
                const bool hit = (jb != ib) && (ovx > 0.0f) && (ovy > 0.0f);
                const bool ux  = ovx <= ovy;
                ax += (hit && ux)  ? 0.5f * ovx * (dax >= 0.0f ? 1.0f : -1.0f) : 0.0f;
                ay += (hit && !ux) ? 0.5f * ovy * (day >= 0.0f ? 1.0f : -1.0f) : 0.0f;
            }
        }
    }

    // ---- block reduction: 4 waves -> 1 partial per body ----
    __shared__ float sax[4][64];
    __shared__ float say[4][64];
    sax[w][lane] = ax;
    say[w][lane] = ay;
    __syncthreads();
    if (w == 0 && i < Ntot) {
        float tx = sax[0][lane] + sax[1][lane] + sax[2][lane] + sax[3][lane];
        float ty = say[0][lane] + say[1][lane] + say[2][lane] + say[3][lane];
        if (blockIdx.y == 0) { tx += mx; ty += my; }     // fold base position once
        atomicAdd(&out[2 * i],     tx);
        atomicAdd(&out[2 * i + 1], ty);
    }
}

extern "C" void kernel_launch(void* const* d_in, const int* in_sizes, int n_in,
                              void* d_out, int out_size, void* d_ws, size_t ws_size,
                              hipStream_t stream) {
    (void)n_in; (void)d_ws; (void)ws_size;

    const float2* cpos  = (const float2*)d_in[0];
    const float*  crad  = (const float*) d_in[1];
    const float2* apos  = (const float2*)d_in[2];
    const float2* ahalf = (const float2*)d_in[3];

    const int Nc   = in_sizes[1];       // 4096
    const int Na   = in_sizes[2] / 2;   // 2048
    const int Ntot = Nc + Na;           // 6144

    // out accumulates via atomics -> zero it (async; graph-capture safe)
    hipMemsetAsync(d_out, 0, (size_t)out_size * sizeof(float), stream);

    const int gx = (Ntot + 63) / 64;      // 96 body groups
    const int gy = (Ntot + 255) / 256;    // 24 partner super-chunks
    dim3 grid(gx, gy, 1);
    collide<<<grid, 256, 0, stream>>>(cpos, crad, apos, ahalf, (float*)d_out, Nc, Na);
}

// Round 5
// 78.183 us; speedup vs baseline: 1.0705x; 1.0032x over previous
//
#include <hip/hip_runtime.h>
#include <math.h>

#define EPS 1e-9f

// P[i]: circle i<Nc -> (x, y, radius, 0); box -> (x, y, half.x, half.y).
// Also seeds out with base positions (collide only atomically adds corrections).
// Rebuilt every call: d_ws is re-poisoned by the harness before each launch.
__global__ void prep(const float2* __restrict__ cpos,
                     const float*  __restrict__ crad,
                     const float2* __restrict__ apos,
                     const float2* __restrict__ ahalf,
                     float4* __restrict__ P,
                     float2* __restrict__ out,
                     int Nc, int Ntot) {
    int i = blockIdx.x * blockDim.x + threadIdx.x;
    if (i >= Ntot) return;
    if (i < Nc) {
        const float2 p = cpos[i];
        P[i]   = make_float4(p.x, p.y, crad[i], 0.0f);
        out[i] = p;
    } else {
        const float2 a = apos[i - Nc];
        const float2 h = ahalf[i - Nc];
        P[i]   = make_float4(a.x, a.y, h.x, h.y);
        out[i] = a;
    }
}

// Lane-per-body, wave-per-(64-body group x 64-partner chunk).
// Partner index is wave-uniform via readfirstlane -> s_load_dwordx4/x16:
// the partner stream rides the scalar pipe; VALU does only pair math.
// Body-type and partner-type branches are uniform (64-aligned groups).
// 4 waves of a block share a body group -> LDS-reduce -> 2 atomics/body/block.
__global__ __launch_bounds__(256)
void collide(const float4* __restrict__ P,
             float* __restrict__ out,
             int Nc, int Ntot) {
    const int lane  = threadIdx.x & 63;
    const int w     = __builtin_amdgcn_readfirstlane(threadIdx.x >> 6);
    const int i     = (blockIdx.x << 6) + lane;           // my body
    const int jbase = (blockIdx.y * 4 + w) << 6;          // wave's partner chunk (uniform)

    const float4 me = P[i];                               // per-lane, coalesced
    float ax = 0.0f, ay = 0.0f;

    const bool body_circle = ((int)(blockIdx.x << 6)) < Nc;   // uniform
    const bool part_circle = (jbase < Nc);                    // uniform

    if (body_circle) {
        const float px = me.x, py = me.y, ri = me.z;
        if (part_circle) {
            // circle vs circle (self-pair: d2==0 -> excluded by d2>EPS, no j!=i needed)
            #pragma unroll 8
            for (int k = 0; k < 64; ++k) {
                const float4 q = P[jbase + k];            // uniform -> s_load
                const float dx = px - q.x, dy = py - q.y;
                const float d2 = fmaf(dx, dx, dy * dy);
                const float r  = __builtin_amdgcn_rsqf(d2);
                const float pen = (ri + q.z) - d2 * r;
                const float s = (d2 > EPS && pen > 0.0f) ? 0.5f * pen * r : 0.0f;
                ax = fmaf(s, dx, ax);
                ay = fmaf(s, dy, ay);
            }
        } else {
            // circle vs box (push on circle)
            #pragma unroll 8
            for (int k = 0; k < 64; ++k) {
                const float4 q = P[jbase + k];
                const float rx = px - q.x, ry = py - q.y;
                const float cx = fminf(fmaxf(rx, -q.z), q.z);
                const float cy = fminf(fmaxf(ry, -q.w), q.w);
                const float dx = rx - cx, dy = ry - cy;
                const float d2 = fmaf(dx, dx, dy * dy);
                const float r  = __builtin_amdgcn_rsqf(d2);
                const float pen = ri - d2 * r;
                const float s = (d2 > EPS && pen > 0.0f) ? 0.5f * pen * r : 0.0f;
                ax = fmaf(s, dx, ax);
                ay = fmaf(s, dy, ay);
            }
        }
    } else {
        const float bx = me.x, by = me.y, hx = me.z, hy = me.w;
        if (part_circle) {
            // circle vs box: equal-and-opposite on the box
            #pragma unroll 8
            for (int k = 0; k < 64; ++k) {
                const float4 q = P[jbase + k];
                const float rx = q.x - bx, ry = q.y - by;
                const float cx = fminf(fmaxf(rx, -hx), hx);
                const float cy = fminf(fmaxf(ry, -hy), hy);
                const float dx = rx - cx, dy = ry - cy;
                const float d2 = fmaf(dx, dx, dy * dy);
                const float r  = __builtin_amdgcn_rsqf(d2);
                const float pen = q.z - d2 * r;
                const float s = (d2 > EPS && pen > 0.0f) ? -0.5f * pen * r : 0.0f;
                ax = fmaf(s, dx, ax);
                ay = fmaf(s, dy, ay);
            }
        } else {
            // box vs box (minimum-overlap axis; self-pair must be excluded)
            #pragma unroll 8
            for (int k = 0; k < 64; ++k) {
                const int j = jbase + k;                  // uniform
                const float4 q = P[j];
                const float dax = bx - q.x, day = by - q.y;
                const float ovx = hx + q.z - fabsf(dax);
                const float ovy = hy + q.w - fabsf(day);
                const bool hit = (j != i) && (ovx > 0.0f) && (ovy > 0.0f);
                const bool ux  = ovx <= ovy;
                ax += (hit && ux)  ? 0.5f * ovx * (dax >= 0.0f ? 1.0f : -1.0f) : 0.0f;
                ay += (hit && !ux) ? 0.5f * ovy * (day >= 0.0f ? 1.0f : -1.0f) : 0.0f;
            }
        }
    }

    // block reduction: 4 waves -> 1 partial per body -> 2 atomics
    __shared__ float sax[4][64];
    __shared__ float say[4][64];
    sax[w][lane] = ax;
    say[w][lane] = ay;
    __syncthreads();
    if (w == 0) {
        const float tx = sax[0][lane] + sax[1][lane] + sax[2][lane] + sax[3][lane];
        const float ty = say[0][lane] + say[1][lane] + say[2][lane] + say[3][lane];
        atomicAdd(&out[2 * i],     tx);
        atomicAdd(&out[2 * i + 1], ty);
    }
}

extern "C" void kernel_launch(void* const* d_in, const int* in_sizes, int n_in,
                              void* d_out, int out_size, void* d_ws, size_t ws_size,
                              hipStream_t stream) {
    (void)n_in; (void)out_size; (void)ws_size;

    const float2* cpos  = (const float2*)d_in[0];
    const float*  crad  = (const float*) d_in[1];
    const float2* apos  = (const float2*)d_in[2];
    const float2* ahalf = (const float2*)d_in[3];

    const int Nc   = in_sizes[1];       // 4096
    const int Na   = in_sizes[2] / 2;   // 2048
    const int Ntot = Nc + Na;           // 6144 (= 96 * 64 exactly)

    float4* P = (float4*)d_ws;

    prep<<<(Ntot + 255) / 256, 256, 0, stream>>>(cpos, crad, apos, ahalf,
                                                 P, (float2*)d_out, Nc, Ntot);

    // 96 body groups x 24 blocks (4 wave-chunks each) = all 96x96 wave tiles
    const int gx = (Ntot + 63) / 64;      // 96
    const int gy = (Ntot + 255) / 256;    // 24
    dim3 grid(gx, gy, 1);
    collide<<<grid, 256, 0, stream>>>(P, (float*)d_out, Nc, Ntot);
}